// Round 2
// baseline (942.180 us; speedup 1.0000x reference)
//
#include <hip/hip_runtime.h>
#include <hip/hip_bf16.h>
#include <math.h>

typedef unsigned short ushort_t;
typedef __bf16 bf16x8 __attribute__((ext_vector_type(8)));
typedef float floatx4 __attribute__((ext_vector_type(4)));
typedef float floatx8 __attribute__((ext_vector_type(8)));

#define NEG_BIG -1000000000.0f

__device__ __forceinline__ float b2f(ushort_t u) {
  union { unsigned int i; float f; } v;
  v.i = ((unsigned int)u) << 16;
  return v.f;
}
__device__ __forceinline__ ushort_t f2b(float f) {
  union { float f; unsigned int i; } v;
  v.f = f;
  unsigned int r = v.i + 0x7fffu + ((v.i >> 16) & 1u);  // round-nearest-even
  return (ushort_t)(r >> 16);
}

__device__ __forceinline__ float loadC(const float* p) { return *p; }
__device__ __forceinline__ float loadC(const ushort_t* p) { return b2f(*p); }
__device__ __forceinline__ void storeC(float* p, float v) { *p = v; }
__device__ __forceinline__ void storeC(ushort_t* p, float v) { *p = f2b(v); }

// ---------------------------------------------------------------------------
// Weight transpose + fp32->bf16 convert: Wt[512][4096] bf16.
// Rows 0..255 = w_kv columns, rows 256..511 = w_gate columns.
// ---------------------------------------------------------------------------
__global__ __launch_bounds__(256) void transpose_w_kernel(
    const float* __restrict__ w_kv, const float* __restrict__ w_gate,
    ushort_t* __restrict__ Wt) {
  __shared__ float tile[64][65];   // +1 pad: conflict-free transposed read
  const int K0 = blockIdx.x * 64;  // grid.x = 64  (K = 4096)
  const int N0c = blockIdx.y * 64; // grid.y = 8   (Ncat = 512)
  const float* src = (N0c < 256) ? w_kv : w_gate;
  const int N0 = N0c & 255;
  const int t = threadIdx.x;
#pragma unroll
  for (int i = 0; i < 16; ++i) {
    int l = t + 256 * i;
    int r = l >> 6, c = l & 63;
    tile[r][c] = src[(size_t)(K0 + r) * 256 + N0 + c];  // coalesced in c
  }
  __syncthreads();
#pragma unroll
  for (int i = 0; i < 16; ++i) {
    int l = t + 256 * i;
    int r = l >> 6, c = l & 63;
    Wt[(size_t)(N0c + r) * 4096 + K0 + c] = f2b(tile[c][r]);  // coalesced in c
  }
}

// ---------------------------------------------------------------------------
// GEMM: C[32768][512] = hidden_f32[32768][4096] @ Wt^T  (Wt is [512][4096] bf16)
// 128x128 tile, BK=64, 4 waves, 4x4 16x16x32 bf16 MFMA accumulators.
// A: fp32 global loads -> bf16 convert -> ds_write_b128 (fused conversion).
// B: async global_load_lds width-16 from bf16 Wt.
// ---------------------------------------------------------------------------
template <typename CT>
__global__ __launch_bounds__(256, 2) void gemm_kernel(
    const float* __restrict__ A,      // [32768][4096] fp32
    const ushort_t* __restrict__ Bt,  // [512][4096] bf16
    CT* __restrict__ C) {             // [32768][512]
  constexpr int K = 4096;
  __shared__ __align__(16) ushort_t As[128 * 64];  // [m][k]
  __shared__ __align__(16) ushort_t Bs[128 * 64];  // [n][k]

  const int mt = blockIdx.x >> 2;  // 256 m-tiles
  const int nt = blockIdx.x & 3;   // 4 n-tiles (fast-varying: A-tile L2 reuse)
  const int m0 = mt * 128, n0 = nt * 128;
  const int tid = threadIdx.x;
  const int w = tid >> 6, lane = tid & 63;
  const int wm = w >> 1, wn = w & 1;   // 2x2 wave grid, 64x64 each
  const int sr = lane >> 3;            // B staging row within 8-row chunk
  const int sc = (lane & 7) * 8;       // B staging k-offset (8 bf16 = 16B)
  const int ar = tid >> 3;             // A staging row within 32-row pass
  const int ac = (tid & 7) * 8;        // A staging k-offset (8 fp32 = 32B)
  const int q = lane >> 4, sid = lane & 15;

  floatx4 acc[4][4];
#pragma unroll
  for (int i = 0; i < 4; ++i)
#pragma unroll
    for (int j = 0; j < 4; ++j) acc[i][j] = (floatx4)0.0f;

  for (int kt = 0; kt < K; kt += 64) {
    __syncthreads();
    // B tile: async bf16 staging (16 chunks x 8 rows, wave-uniform LDS base)
#pragma unroll
    for (int i = 0; i < 4; ++i) {
      const int chunk = i * 4 + w;
      const int row = chunk * 8 + sr;
      const ushort_t* g = Bt + (size_t)(n0 + row) * K + kt + sc;
      __builtin_amdgcn_global_load_lds(
          (const __attribute__((address_space(1))) void*)g,
          (__attribute__((address_space(3))) void*)(Bs + chunk * 512), 16, 0, 0);
    }
    // A tile: fp32 load -> bf16 convert -> LDS (4 passes x 32 rows)
#pragma unroll
    for (int p = 0; p < 4; ++p) {
      const int row = p * 32 + ar;  // 0..127
      const float* g = A + (size_t)(m0 + row) * K + kt + ac;
      floatx8 f = *(const floatx8*)g;            // 2x global_load_dwordx4
      bf16x8 h = __builtin_convertvector(f, bf16x8);
      *(bf16x8*)(As + row * 64 + ac) = h;        // ds_write_b128
    }
    __syncthreads();  // drains vmcnt (B staging) + lgkmcnt (A writes)

#pragma unroll
    for (int ks = 0; ks < 64; ks += 32) {
      bf16x8 af[4], bfr[4];
#pragma unroll
      for (int i = 0; i < 4; ++i)
        af[i] = *(const bf16x8*)(As + (wm * 64 + i * 16 + sid) * 64 + ks + q * 8);
#pragma unroll
      for (int j = 0; j < 4; ++j)
        bfr[j] = *(const bf16x8*)(Bs + (wn * 64 + j * 16 + sid) * 64 + ks + q * 8);
#pragma unroll
      for (int i = 0; i < 4; ++i)
#pragma unroll
        for (int j = 0; j < 4; ++j)
          acc[i][j] = __builtin_amdgcn_mfma_f32_16x16x32_bf16(af[i], bfr[j],
                                                              acc[i][j], 0, 0, 0);
    }
  }

  // Epilogue. C/D layout (m89-verified): col = lane&15, row = (lane>>4)*4 + reg
#pragma unroll
  for (int i = 0; i < 4; ++i) {
#pragma unroll
    for (int j = 0; j < 4; ++j) {
#pragma unroll
      for (int r = 0; r < 4; ++r) {
        const int row = m0 + wm * 64 + i * 16 + q * 4 + r;
        const int col = n0 + wn * 64 + j * 16 + sid;
        storeC(&C[(size_t)row * 512 + col], acc[i][j][r]);
      }
    }
  }
}

// ---------------------------------------------------------------------------
// Pool + RoPE. One block per (b, chunk j): online softmax over the 64-entry
// window per head-dim column, then interleaved RoPE on the last 64 dims.
// C columns: [0:128)=kv_lo [128:256)=kv_hi [256:384)=g_lo [384:512)=g_hi
// ---------------------------------------------------------------------------
template <typename CT>
__global__ __launch_bounds__(128) void pool_rope_kernel(
    const CT* __restrict__ C,       // [32768][512]
    const float* __restrict__ pb,   // [64][128] fp32
    float* __restrict__ out) {      // [4*256][128] fp32
  const int blk = blockIdx.x;  // b*256 + j
  const int j = blk & 255;
  const int d = threadIdx.x;   // 0..127

  const size_t base_hi = (size_t)blk * 32 * 512;  // row (b*8192 + j*32)
  const size_t base_lo = base_hi - (size_t)32 * 512;

  float m = -INFINITY, l = 0.f, o = 0.f;
#pragma unroll 8
  for (int t = 0; t < 64; ++t) {
    float g, kv;
    const float bias = pb[t * 128 + d];
    if (t < 32) {
      if (j == 0) {
        g = NEG_BIG;
        kv = 0.f;
      } else {
        g = loadC(&C[base_lo + (size_t)t * 512 + 256 + d]);
        kv = loadC(&C[base_lo + (size_t)t * 512 + d]);
      }
    } else {
      const int tt = t - 32;
      g = loadC(&C[base_hi + (size_t)tt * 512 + 384 + d]);
      kv = loadC(&C[base_hi + (size_t)tt * 512 + 128 + d]);
    }
    g += bias;
    const float mn = fmaxf(m, g);
    const float s = __expf(m - mn);   // exp(-inf)=0 handles first iter
    const float p = __expf(g - mn);
    l = l * s + p;
    o = o * s + p * kv;
    m = mn;
  }
  const float pooled = o / l;

  float res;
  if (d < 64) {
    res = pooled;  // nope part
  } else {
    const int rho = d - 64;
    const int i2 = rho >> 1;
    const float pos = (float)(j * 32);
    const float inv = powf(10000.0f, -(float)(2 * i2) / 64.0f);
    const float f = pos * inv;
    const float c = cosf(f), s2 = sinf(f);
    const float partner = __shfl_xor(pooled, 1, 64);  // pair within wave 1
    // out[2i] = x[2i]*c - x[2i+1]*s ; out[2i+1] = x[2i+1]*c + x[2i]*s
    res = (rho & 1) ? (pooled * c + partner * s2) : (pooled * c - partner * s2);
  }
  out[(size_t)blk * 128 + d] = res;
}

// ---------------------------------------------------------------------------
extern "C" void kernel_launch(void* const* d_in, const int* in_sizes, int n_in,
                              void* d_out, int out_size, void* d_ws,
                              size_t ws_size, hipStream_t stream) {
  (void)in_sizes; (void)n_in; (void)out_size;
  const float* hidden = (const float*)d_in[0];  // [4][8192][4096] fp32
  const float* w_kv = (const float*)d_in[1];    // [4096][256] fp32
  const float* w_gate = (const float*)d_in[2];  // [4096][256] fp32
  const float* pb = (const float*)d_in[3];      // [64][128] fp32
  float* out = (float*)d_out;                   // [4][256][128] fp32

  ushort_t* Wt = (ushort_t*)d_ws;  // 512*4096*2 = 4 MiB
  const size_t wt_bytes = (size_t)512 * 4096 * sizeof(ushort_t);
  char* cbase = (char*)d_ws + wt_bytes;
  const size_t c_elems = (size_t)32768 * 512;

  transpose_w_kernel<<<dim3(64, 8), 256, 0, stream>>>(w_kv, w_gate, Wt);

  if (ws_size >= wt_bytes + c_elems * sizeof(float)) {
    float* C = (float*)cbase;  // 67 MiB fp32 intermediate
    gemm_kernel<float><<<dim3(1024), 256, 0, stream>>>(hidden, Wt, C);
    pool_rope_kernel<float><<<dim3(1024), 128, 0, stream>>>(C, pb, out);
  } else {
    ushort_t* Cb = (ushort_t*)cbase;  // 33.5 MiB bf16 fallback
    gemm_kernel<ushort_t><<<dim3(1024), 256, 0, stream>>>(hidden, Wt, Cb);
    pool_rope_kernel<ushort_t><<<dim3(1024), 128, 0, stream>>>(Cb, pb, out);
  }
}